// Round 1
// baseline (274.959 us; speedup 1.0000x reference)
//
#include <hip/hip_runtime.h>
#include <math.h>

// Problem constants (reference: B=2048, L=16384, WINDOW=30)
constexpr int Bn  = 2048;
constexpr int L   = 16384;
constexpr int W   = 30;
constexpr int NT  = 256;          // threads per block (one block per row)
constexpr int CPT = L / NT;       // 64 elements (window starts) per thread
constexpr int NWIN = L - W + 1;   // 16355 valid window starts

// LDS padding: +1 float per 64 to break the 64-stride bank pattern.
// lane t reads 65*t + i -> bank (t + i) % 32: conflict-free within 32 lanes,
// 2-way alias across half-waves (free per m136).
__device__ __forceinline__ int padidx(int j) { return j + (j >> 6); }

__global__ __launch_bounds__(NT, 2)
void winmax_kernel(const float* __restrict__ x,
                   const float* __restrict__ m,
                   float* __restrict__ out) {
    __shared__ float prob[L + (L >> 6)];   // 16640 floats = 65 KiB
    __shared__ float wmax[NT / 64];

    const int row = blockIdx.x;
    const int t   = threadIdx.x;

    const float4* x4 = (const float4*)(x + (size_t)row * L);
    const float4* m4 = (const float4*)(m + (size_t)row * L);

    // ---- Stage: prob = sigmoid(x) * mask into LDS, coalesced float4 loads ----
    #pragma unroll
    for (int k = 0; k < CPT / 4; ++k) {        // 16 iterations
        const int vi = k * NT + t;             // float4 index within row
        const float4 xv = x4[vi];
        const float4 mv = m4[vi];
        const int j = vi * 4;
        const int p = j + (j >> 6);            // j%4==0 and 4|64 -> all 4 in same pad-block
        prob[p + 0] = mv.x * __builtin_amdgcn_rcpf(1.0f + __expf(-xv.x));
        prob[p + 1] = mv.y * __builtin_amdgcn_rcpf(1.0f + __expf(-xv.y));
        prob[p + 2] = mv.z * __builtin_amdgcn_rcpf(1.0f + __expf(-xv.z));
        prob[p + 3] = mv.w * __builtin_amdgcn_rcpf(1.0f + __expf(-xv.w));
    }
    __syncthreads();

    // ---- Sliding window: thread t owns starts [64t, 64t+63] ∩ [0, NWIN) ----
    const int s0 = t * CPT;
    float sum = 0.0f;
    #pragma unroll
    for (int i = 0; i < W; ++i)                // s0+i <= 16349 < L, always valid
        sum += prob[padidx(s0 + i)];
    float best = sum;

    const int nwin = min(CPT, NWIN - s0);      // 64 for t<255, 35 for t==255
    for (int i = 1; i < nwin; ++i) {
        sum += prob[padidx(s0 + i - 1 + W)] - prob[padidx(s0 + i - 1)];
        best = fmaxf(best, sum);
    }
    best *= (1.0f / W);

    // ---- Block max-reduce: wave shuffle then cross-wave via LDS ----
    #pragma unroll
    for (int off = 32; off > 0; off >>= 1)
        best = fmaxf(best, __shfl_down(best, off, 64));
    if ((t & 63) == 0) wmax[t >> 6] = best;
    __syncthreads();
    if (t == 0) {
        float r = wmax[0];
        #pragma unroll
        for (int w = 1; w < NT / 64; ++w) r = fmaxf(r, wmax[w]);
        out[row] = r;
    }
}

extern "C" void kernel_launch(void* const* d_in, const int* in_sizes, int n_in,
                              void* d_out, int out_size, void* d_ws, size_t ws_size,
                              hipStream_t stream) {
    const float* x = (const float*)d_in[0];
    const float* m = (const float*)d_in[1];
    float* out = (float*)d_out;
    winmax_kernel<<<Bn, NT, 0, stream>>>(x, m, out);
}